// Round 12
// baseline (322.851 us; speedup 1.0000x reference)
//
#include <hip/hip_runtime.h>
#include <hip/hip_bf16.h>

#define B_ 32
#define T_ 4096
#define H_ 512
#define M_TILE 64    // 2 t x 32 b per tile
#define TPB 8        // tiles per block
#define NBLK 256     // 1 block per CU; NBLK*TPB*M_TILE = 131072 rows
#define NTHREADS 512

typedef __attribute__((ext_vector_type(8))) short short8;
typedef __attribute__((ext_vector_type(8))) __bf16 bf16x8;
typedef __attribute__((ext_vector_type(4))) float f32x4;

__device__ __forceinline__ short f2bf(float f) {
    unsigned u = __builtin_bit_cast(unsigned, f);
    u = (u + 0x7fffu + ((u >> 16) & 1u)) >> 16;
    return (short)u;
}

// packed f32->bf16 (RNE): 8 f32 -> 8 bf16 (16B), 4 instructions
__device__ __forceinline__ short8 pack8(f32x4 a, f32x4 b) {
    union { unsigned u[4]; short8 s; } r;
    asm("v_cvt_pk_bf16_f32 %0, %1, %2" : "=v"(r.u[0]) : "v"(a[0]), "v"(a[1]));
    asm("v_cvt_pk_bf16_f32 %0, %1, %2" : "=v"(r.u[1]) : "v"(a[2]), "v"(a[3]));
    asm("v_cvt_pk_bf16_f32 %0, %1, %2" : "=v"(r.u[2]) : "v"(b[0]), "v"(b[1]));
    asm("v_cvt_pk_bf16_f32 %0, %1, %2" : "=v"(r.u[3]) : "v"(b[2]), "v"(b[3]));
    return r.s;
}

// ---- prep: W2 -> bf16 fragment-packed (verified layout R4-R10, unchanged) ----
// w2f[c][ck][ni][lane][j]: h = c*64+ni*16+(lane&15), k = ck*32+(lane>>4)*8+j
__global__ void prep_w2f(const float* __restrict__ W, short* __restrict__ w2f) {
    int idx = blockIdx.x * 256 + threadIdx.x;   // 0 .. 262143
    int j    = idx & 7;
    int lane = (idx >> 3) & 63;
    int ni   = (idx >> 9) & 3;
    int ck   = (idx >> 11) & 15;
    int c    = (idx >> 15) & 7;
    int h = c * 64 + ni * 16 + (lane & 15);
    int k = ck * 32 + (lane >> 4) * 8 + j;
    w2f[idx] = f2bf(W[h * (2 * H_) + H_ + k]);
}

// ---- prep: hid_proj[b][h] = hidden[b,:]*W1[h,:] + bias[h] (f32 exact) ----
__global__ void prep_hid(const float* __restrict__ hidden,
                         const float* __restrict__ W,
                         const float* __restrict__ bias,
                         float* __restrict__ hidproj) {
    __shared__ float hrow[H_];
    int b = blockIdx.y;
    int h = blockIdx.x * 128 + threadIdx.x;
    for (int i = threadIdx.x; i < H_; i += 128) hrow[i] = hidden[b * H_ + i];
    __syncthreads();
    const float* wr = W + (size_t)h * (2 * H_);
    float acc = bias[h];
#pragma unroll 4
    for (int k = 0; k < H_; k += 4) {
        acc += hrow[k]     * wr[k];
        acc += hrow[k + 1] * wr[k + 1];
        acc += hrow[k + 2] * wr[k + 2];
        acc += hrow[k + 3] * wr[k + 3];
    }
    hidproj[b * H_ + h] = acc;
}

// ---- main: persistent 1-block/CU, full-K dbuf, loads in flight across barriers ----
__global__ __launch_bounds__(NTHREADS, 1)
void attn_main(const float* __restrict__ enc,      // [T*B][H] f32, tile-contiguous
               const float* __restrict__ hidproj,  // [B][H] f32
               const short* __restrict__ w2f,      // frag-packed bf16 W2
               const float* __restrict__ vvec,     // [H]
               float* __restrict__ out)            // [B][T]
{
    __shared__ __align__(16) short lds_a[2][M_TILE * H_];  // 2 x 64 KB
    __shared__ float red[2][NTHREADS];                      // 4 KB

    const int tid  = threadIdx.x;
    const int lane = tid & 63;
    const int wid  = tid >> 6;          // 0..7: wave owns h-block wid AND staging row group
    const int lo   = lane & 15;
    const int hi4  = lane >> 4;
    const int xm   = lo & 7;
    const int gbase = blockIdx.x * TPB;

    // staging constants: pass p stages row = p*8+wid; global f32 = g*32768 + p*4096 + aoff
    const int aoff   = wid * 512 + lane * 8;
    const int wr_off = (wid << 10) + ((lane ^ wid) << 4);   // byte, within pass stride 8KB

    // B stream base
    const short* wbase = w2f + (size_t)wid * 32768 + lane * 8;

    // hoisted epilogue constants
    float hp[2][4][4];
#pragma unroll
    for (int par = 0; par < 2; ++par)
#pragma unroll
        for (int j = 0; j < 4; ++j) {
            int b = par * 16 + hi4 * 4 + j;
#pragma unroll
            for (int ni = 0; ni < 4; ++ni)
                hp[par][j][ni] = hidproj[b * H_ + wid * 64 + ni * 16 + lo];
        }
    float vh[4];
#pragma unroll
    for (int ni = 0; ni < 4; ++ni) vh[ni] = vvec[wid * 64 + ni * 16 + lo];

    // stage registers (A of tile t+1 in flight)
    f32x4 sA0, sB0, sA1, sB1, sA2, sB2, sA3, sB3, sA4, sB4, sA5, sB5, sA6, sB6, sA7, sB7;

#define LOADS(G)                                                                  \
    { const float* ap_ = enc + (size_t)(G) * 32768 + aoff;                        \
      sA0 = *(const f32x4*)(ap_ +     0); sB0 = *(const f32x4*)(ap_ +     4);     \
      sA1 = *(const f32x4*)(ap_ +  4096); sB1 = *(const f32x4*)(ap_ +  4100);     \
      sA2 = *(const f32x4*)(ap_ +  8192); sB2 = *(const f32x4*)(ap_ +  8196);     \
      sA3 = *(const f32x4*)(ap_ + 12288); sB3 = *(const f32x4*)(ap_ + 12292);     \
      sA4 = *(const f32x4*)(ap_ + 16384); sB4 = *(const f32x4*)(ap_ + 16388);     \
      sA5 = *(const f32x4*)(ap_ + 20480); sB5 = *(const f32x4*)(ap_ + 20484);     \
      sA6 = *(const f32x4*)(ap_ + 24576); sB6 = *(const f32x4*)(ap_ + 24580);     \
      sA7 = *(const f32x4*)(ap_ + 28672); sB7 = *(const f32x4*)(ap_ + 28676); }

// NOTE: macro-local renamed wbp_ — R11 crashed because `char* wb = (char*)(wb)+...`
// self-initialized a shadowing local (UB) when invoked as WRITES(wb).
#define WRITES(WB)                                                                \
    { char* wbp_ = (char*)(WB) + wr_off;                                          \
      *(short8*)(wbp_ +      0) = pack8(sA0, sB0);                                \
      *(short8*)(wbp_ +   8192) = pack8(sA1, sB1);                                \
      *(short8*)(wbp_ +  16384) = pack8(sA2, sB2);                                \
      *(short8*)(wbp_ +  24576) = pack8(sA3, sB3);                                \
      *(short8*)(wbp_ +  32768) = pack8(sA4, sB4);                                \
      *(short8*)(wbp_ +  40960) = pack8(sA5, sB5);                                \
      *(short8*)(wbp_ +  49152) = pack8(sA6, sB6);                                \
      *(short8*)(wbp_ +  57344) = pack8(sA7, sB7); }

    // ---- prologue: stage tile 0, issue loads for tile 1, barrier ----
    LOADS(gbase)
    WRITES(&lds_a[0][0])
    if (TPB > 1) LOADS(gbase + 1)
    __builtin_amdgcn_sched_barrier(0);
    asm volatile("s_waitcnt lgkmcnt(0)" ::: "memory");
    __builtin_amdgcn_s_barrier();

#define KSUB(S4, BQ)                                                              \
    {                                                                             \
        bf16x8 af[4];                                                             \
        _Pragma("unroll")                                                         \
        for (int mi = 0; mi < 4; ++mi) {                                          \
            int r = mi * 16 + lo;                                                 \
            af[mi] = *(const bf16x8*)&rb[r * 512 + ((((S4) + hi4) ^ xm) << 3)];   \
        }                                                                         \
        __builtin_amdgcn_s_setprio(1);                                            \
        _Pragma("unroll")                                                         \
        for (int mi = 0; mi < 4; ++mi)                                            \
            _Pragma("unroll")                                                     \
            for (int ni = 0; ni < 4; ++ni)                                        \
                acc[mi][ni] = __builtin_amdgcn_mfma_f32_16x16x32_bf16(            \
                    af[mi], BQ[ni], acc[mi][ni], 0, 0, 0);                        \
        __builtin_amdgcn_s_setprio(0);                                            \
    }

#define KSTEP(KK)                                                                 \
    {                                                                             \
        _Pragma("unroll")                                                         \
        for (int ni = 0; ni < 4; ++ni)                                            \
            bqB[ni] = *(const bf16x8*)(wbase + (((KK) * 2 + 1) * 4 + ni) * 512);  \
        KSUB((KK) * 8, bqA)                                                       \
        if ((KK) < 7) {                                                           \
            _Pragma("unroll")                                                     \
            for (int ni = 0; ni < 4; ++ni)                                        \
                bqA[ni] = *(const bf16x8*)(wbase + (((KK) * 2 + 2) * 4 + ni) * 512); \
        }                                                                         \
        KSUB((KK) * 8 + 4, bqB)                                                   \
    }

#pragma unroll 1
    for (int lt = 0; lt < TPB; ++lt) {
        const int g = gbase + lt;
        const short* __restrict__ rb = &lds_a[lt & 1][0];
        short* __restrict__ wb = &lds_a[(lt & 1) ^ 1][0];

        f32x4 acc[4][4];
#pragma unroll
        for (int i = 0; i < 4; ++i)
#pragma unroll
            for (int j = 0; j < 4; ++j) acc[i][j] = f32x4{0.f, 0.f, 0.f, 0.f};

        bf16x8 bqA[4], bqB[4];
#pragma unroll
        for (int ni = 0; ni < 4; ++ni) bqA[ni] = *(const bf16x8*)(wbase + ni * 512);

        KSTEP(0) KSTEP(1) KSTEP(2) KSTEP(3) KSTEP(4) KSTEP(5)

        // write staged A(lt+1) into wb; then immediately refill regs with A(lt+2)
        if (lt + 1 < TPB) {
            WRITES(wb)
            if (lt + 2 < TPB) {
                LOADS(g + 2)
                __builtin_amdgcn_sched_barrier(0);
            }
        }

        KSTEP(6) KSTEP(7)

        // ---- per-tile epilogue: energy += hid, softmax over b, v-dot, reduce ----
#pragma unroll
        for (int mi = 0; mi < 4; ++mi)
#pragma unroll
            for (int ni = 0; ni < 4; ++ni)
#pragma unroll
                for (int j = 0; j < 4; ++j)
                    acc[mi][ni][j] += hp[mi & 1][j][ni];

        float scp[4][4];
#pragma unroll
        for (int tl2 = 0; tl2 < 2; ++tl2) {
            const int m0 = tl2 * 2, m1 = tl2 * 2 + 1;
#pragma unroll
            for (int ni = 0; ni < 4; ++ni) {
                float mx = -1e30f;
#pragma unroll
                for (int j = 0; j < 4; ++j) {
                    mx = fmaxf(mx, acc[m0][ni][j]);
                    mx = fmaxf(mx, acc[m1][ni][j]);
                }
                mx = fmaxf(mx, __shfl_xor(mx, 16));
                mx = fmaxf(mx, __shfl_xor(mx, 32));
                float e0[4], e1[4];
                float sum = 0.f;
#pragma unroll
                for (int j = 0; j < 4; ++j) {
                    e0[j] = __expf(acc[m0][ni][j] - mx);
                    e1[j] = __expf(acc[m1][ni][j] - mx);
                    sum += e0[j] + e1[j];
                }
                sum += __shfl_xor(sum, 16);
                sum += __shfl_xor(sum, 32);
                float rs = vh[ni] / sum;
#pragma unroll
                for (int j = 0; j < 4; ++j) {
                    if (ni == 0) { scp[m0][j] = e0[j] * rs; scp[m1][j] = e1[j] * rs; }
                    else         { scp[m0][j] += e0[j] * rs; scp[m1][j] += e1[j] * rs; }
                }
            }
        }

#pragma unroll
        for (int mi = 0; mi < 4; ++mi)
#pragma unroll
            for (int j = 0; j < 4; ++j) {
                float x = scp[mi][j];
                x += __shfl_xor(x, 1);
                x += __shfl_xor(x, 2);
                x += __shfl_xor(x, 4);
                x += __shfl_xor(x, 8);
                scp[mi][j] = x;
            }

        if (lo == 0) {
#pragma unroll
            for (int mi = 0; mi < 4; ++mi)
#pragma unroll
                for (int j = 0; j < 4; ++j)
                    red[lt & 1][wid * 64 + mi * 16 + hi4 * 4 + j] = scp[mi][j];
        }

        // end-of-tile barrier: staged writes + red visible; vmem loads stay in flight
        asm volatile("s_waitcnt lgkmcnt(0)" ::: "memory");
        __builtin_amdgcn_s_barrier();

        if (tid < M_TILE) {
            float s = 0.f;
#pragma unroll
            for (int w = 0; w < 8; ++w) s += red[lt & 1][w * 64 + tid];
            int b   = tid & 31;
            int tl2 = tid >> 5;
            out[(size_t)b * T_ + (g * 2 + tl2)] = fmaxf(s, 0.f);
        }
    }
#undef KSTEP
#undef KSUB
#undef LOADS
#undef WRITES
}

extern "C" void kernel_launch(void* const* d_in, const int* in_sizes, int n_in,
                              void* d_out, int out_size, void* d_ws, size_t ws_size,
                              hipStream_t stream) {
    const float* hidden = (const float*)d_in[0];
    const float* enc    = (const float*)d_in[1];
    const float* W      = (const float*)d_in[2];
    const float* bias   = (const float*)d_in[3];
    const float* v      = (const float*)d_in[4];
    float* out = (float*)d_out;

    float* hidproj = (float*)d_ws;                    // 64 KB
    short* w2f     = (short*)((char*)d_ws + 65536);   // 512 KB

    prep_w2f<<<1024, 256, 0, stream>>>(W, w2f);
    prep_hid<<<dim3(4, 32), 128, 0, stream>>>(hidden, W, bias, hidproj);
    attn_main<<<NBLK, NTHREADS, 0, stream>>>(enc, hidproj, w2f, v, out);
}

// Round 13
// 251.728 us; speedup vs baseline: 1.2825x; 1.2825x over previous
//
#include <hip/hip_runtime.h>
#include <hip/hip_bf16.h>

#define B_ 32
#define T_ 4096
#define H_ 512
#define M_TILE 64    // 2 t x 32 b per tile
#define TPB 8        // tiles per block; NBLK*TPB*M_TILE = 131072 rows
#define NBLK 256     // 1 persistent block per CU
#define NTHREADS 512

typedef __attribute__((ext_vector_type(8))) short short8;
typedef __attribute__((ext_vector_type(8))) __bf16 bf16x8;
typedef __attribute__((ext_vector_type(4))) float f32x4;

__device__ __forceinline__ short f2bf(float f) {
    unsigned u = __builtin_bit_cast(unsigned, f);
    u = (u + 0x7fffu + ((u >> 16) & 1u)) >> 16;
    return (short)u;
}

// packed f32->bf16 (RNE): 8 f32 -> 8 bf16 (16B), 4 instructions
__device__ __forceinline__ short8 pack8(f32x4 a, f32x4 b) {
    union { unsigned u[4]; short8 s; } r;
    asm("v_cvt_pk_bf16_f32 %0, %1, %2" : "=v"(r.u[0]) : "v"(a[0]), "v"(a[1]));
    asm("v_cvt_pk_bf16_f32 %0, %1, %2" : "=v"(r.u[1]) : "v"(a[2]), "v"(a[3]));
    asm("v_cvt_pk_bf16_f32 %0, %1, %2" : "=v"(r.u[2]) : "v"(b[0]), "v"(b[1]));
    asm("v_cvt_pk_bf16_f32 %0, %1, %2" : "=v"(r.u[3]) : "v"(b[2]), "v"(b[3]));
    return r.s;
}

// ---- prep: W2 -> bf16 fragment-packed (verified layout R4-R12, unchanged) ----
// w2f[c][ck][ni][lane][j]: h = c*64+ni*16+(lane&15), k = ck*32+(lane>>4)*8+j
__global__ void prep_w2f(const float* __restrict__ W, short* __restrict__ w2f) {
    int idx = blockIdx.x * 256 + threadIdx.x;   // 0 .. 262143
    int j    = idx & 7;
    int lane = (idx >> 3) & 63;
    int ni   = (idx >> 9) & 3;
    int ck   = (idx >> 11) & 15;
    int c    = (idx >> 15) & 7;
    int h = c * 64 + ni * 16 + (lane & 15);
    int k = ck * 32 + (lane >> 4) * 8 + j;
    w2f[idx] = f2bf(W[h * (2 * H_) + H_ + k]);
}

// ---- prep: hid_proj[b][h] = hidden[b,:]*W1[h,:] + bias[h] (f32 exact) ----
__global__ void prep_hid(const float* __restrict__ hidden,
                         const float* __restrict__ W,
                         const float* __restrict__ bias,
                         float* __restrict__ hidproj) {
    __shared__ float hrow[H_];
    int b = blockIdx.y;
    int h = blockIdx.x * 128 + threadIdx.x;
    for (int i = threadIdx.x; i < H_; i += 128) hrow[i] = hidden[b * H_ + i];
    __syncthreads();
    const float* wr = W + (size_t)h * (2 * H_);
    float acc = bias[h];
#pragma unroll 4
    for (int k = 0; k < H_; k += 4) {
        acc += hrow[k]     * wr[k];
        acc += hrow[k + 1] * wr[k + 1];
        acc += hrow[k + 2] * wr[k + 2];
        acc += hrow[k + 3] * wr[k + 3];
    }
    hidproj[b * H_ + h] = acc;
}

// ---- main: persistent 1-block/CU; A staged as f32 via global_load_lds with
//      pre-swizzled per-lane source; convert-on-read; half-K ping-pong ----
__global__ __launch_bounds__(NTHREADS, 2)
void attn_main(const float* __restrict__ enc,      // [T*B][H] f32, tile-contiguous
               const float* __restrict__ hidproj,  // [B][H] f32
               const short* __restrict__ w2f,      // frag-packed bf16 W2
               const float* __restrict__ vvec,     // [H]
               float* __restrict__ out)            // [B][T]
{
    __shared__ __align__(16) float lds_f[2][M_TILE * 256];  // 2 x 64 KB f32 half-K
    __shared__ float red[2][NTHREADS];                       // 4 KB

    const int tid  = threadIdx.x;
    const int lane = tid & 63;
    const int wid  = tid >> 6;          // 0..7: h-block AND staging row group
    const int lo   = lane & 15;
    const int hi4  = lane >> 4;
    const int xm   = lo & 7;            // read-side chunk XOR (row&7)
    const int lane16 = lane << 4;       // byte
    const int gbase = blockIdx.x * TPB;
    const char* encb = (const char*)enc;

    // B stream base
    const short* wbase = w2f + (size_t)wid * 32768 + lane * 8;

    // hoisted epilogue constants
    float hp[2][4][4];
#pragma unroll
    for (int par = 0; par < 2; ++par)
#pragma unroll
        for (int j = 0; j < 4; ++j) {
            int b = par * 16 + hi4 * 4 + j;
#pragma unroll
            for (int ni = 0; ni < 4; ++ni)
                hp[par][j][ni] = hidproj[b * H_ + wid * 64 + ni * 16 + lo];
        }
    float vh[4];
#pragma unroll
    for (int ni = 0; ni < 4; ++ni) vh[ni] = vvec[wid * 64 + ni * 16 + lo];

    // stage half HF of tile G into BUF: wave stages rows wid*8..wid*8+7.
    // LDS dest linear (HW: lane l at +l*16); global source lane-swizzled so
    // physical chunk l holds logical chunk l^(row&7)  [row&7 == i_ here].
#define STAGE(G, HF, BUF)                                                         \
    { const char* gb_ = encb + (size_t)(G) * 131072 + (HF) * 1024 + wid * 16384;  \
      _Pragma("unroll")                                                           \
      for (int i_ = 0; i_ < 8; ++i_) {                                            \
        __builtin_amdgcn_global_load_lds(                                         \
            (const __attribute__((address_space(1))) void*)                       \
                (gb_ + i_ * 2048 + (lane16 ^ (i_ << 4))),                         \
            (__attribute__((address_space(3))) void*)                             \
                ((char*)(BUF) + (wid * 8 + i_) * 1024),                           \
            16, 0, 0); } }

    // KSUB: ksub S (0..7) of current half from f32 buffer rb, B-frags BQ.
    // frag logical chunks c0 = S*8+hi4*2, c0+1; physical = c ^ (row&7).
#define KSUB(S, BQ)                                                               \
    {                                                                             \
        bf16x8 af_[4];                                                            \
        _Pragma("unroll")                                                         \
        for (int mi = 0; mi < 4; ++mi) {                                          \
            int r_ = mi * 16 + lo;                                                \
            const float* rp_ = rb + r_ * 256;                                     \
            f32x4 a0_ = *(const f32x4*)(rp_ + ((((S) * 8 + hi4 * 2)     ^ xm) << 2)); \
            f32x4 a1_ = *(const f32x4*)(rp_ + ((((S) * 8 + hi4 * 2 + 1) ^ xm) << 2)); \
            af_[mi] = __builtin_bit_cast(bf16x8, pack8(a0_, a1_));                \
        }                                                                         \
        __builtin_amdgcn_s_setprio(1);                                            \
        _Pragma("unroll")                                                         \
        for (int mi = 0; mi < 4; ++mi)                                            \
            _Pragma("unroll")                                                     \
            for (int ni = 0; ni < 4; ++ni)                                        \
                acc[mi][ni] = __builtin_amdgcn_mfma_f32_16x16x32_bf16(            \
                    af_[mi], BQ[ni], acc[mi][ni], 0, 0, 0);                       \
        __builtin_amdgcn_s_setprio(0);                                            \
    }

    // KSTEP: 2 ksubs with 2-deep B ring. CK0 = chunk base of half (0 or 8).
    // KK==3 prefetches NXTC (first chunk of next half / next tile, tile-invariant).
#define KSTEP(CK0, KK, NXTC)                                                      \
    {                                                                             \
        _Pragma("unroll")                                                         \
        for (int ni = 0; ni < 4; ++ni)                                            \
            bqB[ni] = *(const bf16x8*)(wbase + (((CK0) + 2 * (KK) + 1) * 4 + ni) * 512); \
        KSUB(2 * (KK), bqA)                                                       \
        _Pragma("unroll")                                                         \
        for (int ni = 0; ni < 4; ++ni)                                            \
            bqA[ni] = *(const bf16x8*)(wbase +                                    \
                ((((KK) == 3 ? (NXTC) : (CK0) + 2 * (KK) + 2)) * 4 + ni) * 512);  \
        KSUB(2 * (KK) + 1, bqB)                                                   \
    }

#define HALF(CK0, NXTC) KSTEP(CK0, 0, NXTC) KSTEP(CK0, 1, NXTC) KSTEP(CK0, 2, NXTC) KSTEP(CK0, 3, NXTC)

    // ---- prologue: stage tile0 half0 -> buf0; first B chunk ----
    STAGE(gbase, 0, &lds_f[0][0])
    asm volatile("s_waitcnt vmcnt(0)" ::: "memory");
    __builtin_amdgcn_s_barrier();

    bf16x8 bqA[4], bqB[4];
#pragma unroll
    for (int ni = 0; ni < 4; ++ni) bqA[ni] = *(const bf16x8*)(wbase + ni * 512);

#pragma unroll 1
    for (int lt = 0; lt < TPB; ++lt) {
        const int g = gbase + lt;

        f32x4 acc[4][4];
#pragma unroll
        for (int i = 0; i < 4; ++i)
#pragma unroll
            for (int j = 0; j < 4; ++j) acc[i][j] = f32x4{0.f, 0.f, 0.f, 0.f};

        // ==== phase 0: stage half1 -> buf1; compute half0 from buf0 ====
        STAGE(g, 1, &lds_f[1][0])
        __builtin_amdgcn_sched_barrier(0);
        {
            const float* rb = &lds_f[0][0];
            HALF(0, 8)
        }
        asm volatile("s_waitcnt vmcnt(0)" ::: "memory");
        __builtin_amdgcn_s_barrier();

        // ==== phase 1: stage next tile half0 -> buf0; compute half1 from buf1 ====
        if (lt + 1 < TPB) {
            STAGE(g + 1, 0, &lds_f[0][0])
            __builtin_amdgcn_sched_barrier(0);
        }
        {
            const float* rb = &lds_f[1][0];
            HALF(8, 0)
        }

        // ---- per-tile epilogue: energy += hid, softmax over b, v-dot, reduce ----
#pragma unroll
        for (int mi = 0; mi < 4; ++mi)
#pragma unroll
            for (int ni = 0; ni < 4; ++ni)
#pragma unroll
                for (int j = 0; j < 4; ++j)
                    acc[mi][ni][j] += hp[mi & 1][j][ni];

        float scp[4][4];
#pragma unroll
        for (int tl2 = 0; tl2 < 2; ++tl2) {
            const int m0 = tl2 * 2, m1 = tl2 * 2 + 1;
#pragma unroll
            for (int ni = 0; ni < 4; ++ni) {
                float mx = -1e30f;
#pragma unroll
                for (int j = 0; j < 4; ++j) {
                    mx = fmaxf(mx, acc[m0][ni][j]);
                    mx = fmaxf(mx, acc[m1][ni][j]);
                }
                mx = fmaxf(mx, __shfl_xor(mx, 16));
                mx = fmaxf(mx, __shfl_xor(mx, 32));
                float e0[4], e1[4];
                float sum = 0.f;
#pragma unroll
                for (int j = 0; j < 4; ++j) {
                    e0[j] = __expf(acc[m0][ni][j] - mx);
                    e1[j] = __expf(acc[m1][ni][j] - mx);
                    sum += e0[j] + e1[j];
                }
                sum += __shfl_xor(sum, 16);
                sum += __shfl_xor(sum, 32);
                float rs = vh[ni] / sum;   // fold v[h] and 1/denom
#pragma unroll
                for (int j = 0; j < 4; ++j) {
                    if (ni == 0) { scp[m0][j] = e0[j] * rs; scp[m1][j] = e1[j] * rs; }
                    else         { scp[m0][j] += e0[j] * rs; scp[m1][j] += e1[j] * rs; }
                }
            }
        }

#pragma unroll
        for (int mi = 0; mi < 4; ++mi)
#pragma unroll
            for (int j = 0; j < 4; ++j) {
                float x = scp[mi][j];
                x += __shfl_xor(x, 1);
                x += __shfl_xor(x, 2);
                x += __shfl_xor(x, 4);
                x += __shfl_xor(x, 8);
                scp[mi][j] = x;
            }

        if (lo == 0) {
#pragma unroll
            for (int mi = 0; mi < 4; ++mi)
#pragma unroll
                for (int j = 0; j < 4; ++j)
                    red[lt & 1][wid * 64 + mi * 16 + hi4 * 4 + j] = scp[mi][j];
        }

        // end-of-tile barrier: red + staged half0(next) drained; then out-write
        asm volatile("s_waitcnt vmcnt(0) lgkmcnt(0)" ::: "memory");
        __builtin_amdgcn_s_barrier();

        if (tid < M_TILE) {
            float s = 0.f;
#pragma unroll
            for (int w = 0; w < 8; ++w) s += red[lt & 1][w * 64 + tid];
            int b   = tid & 31;
            int tl2 = tid >> 5;
            out[(size_t)b * T_ + (g * 2 + tl2)] = fmaxf(s, 0.f);
        }
    }
#undef HALF
#undef KSTEP
#undef KSUB
#undef STAGE
}

extern "C" void kernel_launch(void* const* d_in, const int* in_sizes, int n_in,
                              void* d_out, int out_size, void* d_ws, size_t ws_size,
                              hipStream_t stream) {
    const float* hidden = (const float*)d_in[0];
    const float* enc    = (const float*)d_in[1];
    const float* W      = (const float*)d_in[2];
    const float* bias   = (const float*)d_in[3];
    const float* v      = (const float*)d_in[4];
    float* out = (float*)d_out;

    float* hidproj = (float*)d_ws;                    // 64 KB
    short* w2f     = (short*)((char*)d_ws + 65536);   // 512 KB

    prep_w2f<<<1024, 256, 0, stream>>>(W, w2f);
    prep_hid<<<dim3(4, 32), 128, 0, stream>>>(hidden, W, bias, hidproj);
    attn_main<<<NBLK, NTHREADS, 0, stream>>>(enc, hidproj, w2f, v, out);
}